// Round 1
// baseline (926.630 us; speedup 1.0000x reference)
//
#include <hip/hip_runtime.h>
#include <hip/hip_bf16.h>
#include <math.h>

#define NITEMS 100000
#define NUSERS 16384
#define GCN 128
#define GEO 32
#define HIDD 256
#define TD 128
#define RK 50

// ============================ Item tower ============================
// hidden = relu([geo | gcn] @ Wi1 + bi1); out = normalize(hidden @ Wi2 + bi2)
// 256 threads/block, 64 items/block. One 64KB LDS buffer reused:
//   phase 1-2: xi[160][XSTR=68] (transposed input tile)
//   phase 3:   hid[64][256] with XOR-swizzled columns (avoids 4-way bank conflict)
#define TI 64
#define XSTR 68

__global__ __launch_bounds__(256) void item_kernel(
    const float* __restrict__ item_feat,
    const float* __restrict__ gcn_item,
    const float* __restrict__ Wg, const float* __restrict__ bg,
    const float* __restrict__ Wi1, const float* __restrict__ bi1,
    const float* __restrict__ Wi2, const float* __restrict__ bi2,
    float* __restrict__ out)
{
  __shared__ float smem[TI * 256];   // 64 KB exactly
  const int tid = threadIdx.x;
  const int tx = tid & 15;
  const int ty = tid >> 4;
  const int i0 = blockIdx.x * TI;

  // ---- stage xi transposed: xi[s][it] = smem[s*XSTR + it]
  for (int idx = tid; idx < TI * GCN; idx += 256) {
    const int it = idx >> 7, c = idx & (GCN - 1);
    const int item = i0 + it;
    smem[(c + GEO) * XSTR + it] = (item < NITEMS) ? gcn_item[(size_t)item * GCN + c] : 0.f;
  }
  for (int idx = tid; idx < TI * GEO; idx += 256) {
    const int it = idx >> 5, g = idx & (GEO - 1);
    const int item = i0 + it;
    float f0 = 0.f, f1 = 0.f;
    if (item < NITEMS) { f0 = item_feat[(size_t)item * 2]; f1 = item_feat[(size_t)item * 2 + 1]; }
    smem[g * XSTR + it] = fmaxf(fmaf(f0, Wg[g], fmaf(f1, Wg[GEO + g], bg[g])), 0.f);
  }
  __syncthreads();

  // ---- GEMM1: acc[4 items][16 hidden cols] per thread
  float acc[4][16];
  {
    float bb[16];
    #pragma unroll
    for (int j = 0; j < 4; ++j) {
      const float4 t4 = ((const float4*)(bi1 + tx * 16))[j];
      bb[4*j] = t4.x; bb[4*j+1] = t4.y; bb[4*j+2] = t4.z; bb[4*j+3] = t4.w;
    }
    #pragma unroll
    for (int a = 0; a < 4; ++a)
      #pragma unroll
      for (int b = 0; b < 16; ++b) acc[a][b] = bb[b];
  }

  #pragma unroll 2
  for (int s = 0; s < GEO + GCN; ++s) {
    const float4 xv = *(const float4*)(&smem[s * XSTR + ty * 4]);
    float w[16];
    const float4* wp = (const float4*)(Wi1 + (size_t)s * HIDD + tx * 16);
    #pragma unroll
    for (int j = 0; j < 4; ++j) {
      const float4 w4 = wp[j];
      w[4*j] = w4.x; w[4*j+1] = w4.y; w[4*j+2] = w4.z; w[4*j+3] = w4.w;
    }
    const float x0 = xv.x, x1 = xv.y, x2 = xv.z, x3 = xv.w;
    #pragma unroll
    for (int b = 0; b < 16; ++b) {
      acc[0][b] = fmaf(x0, w[b], acc[0][b]);
      acc[1][b] = fmaf(x1, w[b], acc[1][b]);
      acc[2][b] = fmaf(x2, w[b], acc[2][b]);
      acc[3][b] = fmaf(x3, w[b], acc[3][b]);
    }
  }

  __syncthreads();  // all xi reads done before overwriting smem

  // ---- store relu(hidden) as hid[it][h ^ swz(it)] (swz flips bits 3..4 -> bank spread)
  #pragma unroll
  for (int a = 0; a < 4; ++a) {
    const int it = ty * 4 + a;
    const int sw = ((it >> 2) & 3) << 3;
    #pragma unroll
    for (int j = 0; j < 4; ++j) {
      const int h0 = tx * 16 + 4 * j;
      float4 v4;
      v4.x = fmaxf(acc[a][4*j+0], 0.f);
      v4.y = fmaxf(acc[a][4*j+1], 0.f);
      v4.z = fmaxf(acc[a][4*j+2], 0.f);
      v4.w = fmaxf(acc[a][4*j+3], 0.f);
      *(float4*)(&smem[(it << 8) + (h0 ^ sw)]) = v4;
    }
  }
  __syncthreads();

  // ---- GEMM2: oacc[4 items][8 out cols]
  float oacc[4][8];
  {
    float ob[8];
    #pragma unroll
    for (int j = 0; j < 2; ++j) {
      const float4 t4 = ((const float4*)(bi2 + tx * 8))[j];
      ob[4*j] = t4.x; ob[4*j+1] = t4.y; ob[4*j+2] = t4.z; ob[4*j+3] = t4.w;
    }
    #pragma unroll
    for (int a = 0; a < 4; ++a)
      #pragma unroll
      for (int j = 0; j < 8; ++j) oacc[a][j] = ob[j];
  }

  #pragma unroll 2
  for (int h = 0; h < HIDD; ++h) {
    float w[8];
    const float4* wp = (const float4*)(Wi2 + (size_t)h * TD + tx * 8);
    {
      const float4 w4 = wp[0]; w[0]=w4.x; w[1]=w4.y; w[2]=w4.z; w[3]=w4.w;
      const float4 w5 = wp[1]; w[4]=w5.x; w[5]=w5.y; w[6]=w5.z; w[7]=w5.w;
    }
    #pragma unroll
    for (int a = 0; a < 4; ++a) {
      const int it = ty * 4 + a;
      const float xh = smem[(it << 8) + (h ^ (((it >> 2) & 3) << 3))];
      #pragma unroll
      for (int j = 0; j < 8; ++j) oacc[a][j] = fmaf(xh, w[j], oacc[a][j]);
    }
  }

  // ---- normalize (dim=1) + store
  #pragma unroll
  for (int a = 0; a < 4; ++a) {
    float ssq = 0.f;
    #pragma unroll
    for (int j = 0; j < 8; ++j) ssq = fmaf(oacc[a][j], oacc[a][j], ssq);
    ssq += __shfl_xor(ssq, 1, 16);
    ssq += __shfl_xor(ssq, 2, 16);
    ssq += __shfl_xor(ssq, 4, 16);
    ssq += __shfl_xor(ssq, 8, 16);
    const float scale = 1.f / fmaxf(sqrtf(ssq), 1e-12f);
    const int item = i0 + ty * 4 + a;
    if (item < NITEMS) {
      float4 o0, o1;
      o0.x = oacc[a][0]*scale; o0.y = oacc[a][1]*scale; o0.z = oacc[a][2]*scale; o0.w = oacc[a][3]*scale;
      o1.x = oacc[a][4]*scale; o1.y = oacc[a][5]*scale; o1.z = oacc[a][6]*scale; o1.w = oacc[a][7]*scale;
      float4* op = (float4*)(out + (size_t)item * TD + tx * 8);
      op[0] = o0; op[1] = o1;
    }
  }
}

// ============================ User side ============================
// Algebraic rewrite: scores[u,j] = h[u,j] . (Wk @ q[u])  (+ q.bk dropped: softmax-invariant)
// 256 threads/block, 16 users/block. Fully fused: q -> qt -> scores -> softmax
// -> rep -> MLP -> normalize.
#define UT 16
#define RS 132    // stride for 128-wide LDS rows (16B aligned, bank-offset 4/row)
#define HS 260    // stride for 256-wide LDS rows

__global__ __launch_bounds__(256) void user_kernel(
    const float* __restrict__ gcn_user,
    const int* __restrict__ user_items,
    const float* __restrict__ Wq, const float* __restrict__ bq,
    const float* __restrict__ Wk,
    const float* __restrict__ Wu1, const float* __restrict__ bu1,
    const float* __restrict__ Wu2, const float* __restrict__ bu2,
    const float* __restrict__ item_emb,
    float* __restrict__ out)
{
  __shared__ float s_gue[UT * RS];
  __shared__ float s_qt [UT * RS];
  __shared__ float s_q  [UT * RS];   // q, later reused for rep
  __shared__ float s_sc [UT * 52];
  __shared__ int   s_idx[UT * RK];
  __shared__ float s_hid[UT * HS];

  const int tid = threadIdx.x;
  const int ul = tid >> 4;
  const int tx = tid & 15;
  const int u0 = blockIdx.x * UT;

  for (int idx = tid; idx < UT * GCN; idx += 256) {
    const int u = idx >> 7, c = idx & (GCN - 1);
    s_gue[u * RS + c] = gcn_user[(size_t)(u0 + u) * GCN + c];
  }
  for (int idx = tid; idx < UT * RK; idx += 256)
    s_idx[idx] = user_items[(size_t)u0 * RK + idx];
  __syncthreads();

  // ---- q = gue @ Wq + bq  (thread: user ul, cols tx*8..+7)
  {
    const int c0 = tx * 8;
    float a0[8];
    {
      const float4 b4 = *(const float4*)(bq + c0);
      const float4 b5 = *(const float4*)(bq + c0 + 4);
      a0[0]=b4.x; a0[1]=b4.y; a0[2]=b4.z; a0[3]=b4.w;
      a0[4]=b5.x; a0[5]=b5.y; a0[6]=b5.z; a0[7]=b5.w;
    }
    for (int g = 0; g < GCN; ++g) {
      const float x = s_gue[ul * RS + g];
      const float4 w4 = *(const float4*)(Wq + (size_t)g * TD + c0);
      const float4 w5 = *(const float4*)(Wq + (size_t)g * TD + c0 + 4);
      a0[0] = fmaf(x, w4.x, a0[0]); a0[1] = fmaf(x, w4.y, a0[1]);
      a0[2] = fmaf(x, w4.z, a0[2]); a0[3] = fmaf(x, w4.w, a0[3]);
      a0[4] = fmaf(x, w5.x, a0[4]); a0[5] = fmaf(x, w5.y, a0[5]);
      a0[6] = fmaf(x, w5.z, a0[6]); a0[7] = fmaf(x, w5.w, a0[7]);
    }
    #pragma unroll
    for (int j = 0; j < 8; ++j) s_q[ul * RS + c0 + j] = a0[j];
  }
  __syncthreads();

  // ---- qt[ul][s] = dot(q[ul], Wk row s)   (thread: 8 s-values)
  {
    const int c0 = tx * 8;
    float a1[8] = {0,0,0,0,0,0,0,0};
    for (int t4 = 0; t4 < TD; t4 += 4) {
      const float4 q4 = *(const float4*)(&s_q[ul * RS + t4]);
      #pragma unroll
      for (int j = 0; j < 8; ++j) {
        const float4 w4 = *(const float4*)(Wk + (size_t)(c0 + j) * TD + t4);
        a1[j] += q4.x*w4.x + q4.y*w4.y + q4.z*w4.z + q4.w*w4.w;
      }
    }
    #pragma unroll
    for (int j = 0; j < 8; ++j) s_qt[ul * RS + c0 + j] = a1[j];
  }
  __syncthreads();

  // ---- scores: one quad of threads per (user,j) dot
  {
    const int qd = tid >> 2, r = tid & 3;
    for (int d = qd; d < UT * RK; d += 64) {
      const int uu = d / RK, j = d - uu * RK;
      const int item = s_idx[uu * RK + j];
      const float* hr = item_emb + (size_t)item * TD + r * 32;
      const float* qr = s_qt + uu * RS + r * 32;
      float p = 0.f;
      #pragma unroll
      for (int i = 0; i < 8; ++i) {
        const float4 h4 = ((const float4*)hr)[i];
        const float4 q4 = ((const float4*)qr)[i];
        p += h4.x*q4.x + h4.y*q4.y + h4.z*q4.z + h4.w*q4.w;
      }
      p += __shfl_xor(p, 1, 4);
      p += __shfl_xor(p, 2, 4);
      if (r == 0) s_sc[uu * 52 + j] = p;
    }
  }
  __syncthreads();

  // ---- softmax over 50 (16 threads per user)
  {
    float m = -3.4e38f;
    for (int j = tx; j < RK; j += 16) m = fmaxf(m, s_sc[ul * 52 + j]);
    #pragma unroll
    for (int d = 1; d < 16; d <<= 1) m = fmaxf(m, __shfl_xor(m, d, 16));
    float ssum = 0.f;
    for (int j = tx; j < RK; j += 16) ssum += __expf(s_sc[ul * 52 + j] - m);
    #pragma unroll
    for (int d = 1; d < 16; d <<= 1) ssum += __shfl_xor(ssum, d, 16);
    const float inv = 1.f / ssum;
    for (int j = tx; j < RK; j += 16) s_sc[ul * 52 + j] = __expf(s_sc[ul * 52 + j] - m) * inv;
  }
  __syncthreads();

  // ---- rep = sum_j alpha_j * h_j   (reuse s_q)
  {
    const int c0 = tx * 8;
    float a2[8] = {0,0,0,0,0,0,0,0};
    for (int j = 0; j < RK; ++j) {
      const float al = s_sc[ul * 52 + j];
      const int item = s_idx[ul * RK + j];
      const float4 h4 = *(const float4*)(item_emb + (size_t)item * TD + c0);
      const float4 h5 = *(const float4*)(item_emb + (size_t)item * TD + c0 + 4);
      a2[0] = fmaf(al, h4.x, a2[0]); a2[1] = fmaf(al, h4.y, a2[1]);
      a2[2] = fmaf(al, h4.z, a2[2]); a2[3] = fmaf(al, h4.w, a2[3]);
      a2[4] = fmaf(al, h5.x, a2[4]); a2[5] = fmaf(al, h5.y, a2[5]);
      a2[6] = fmaf(al, h5.z, a2[6]); a2[7] = fmaf(al, h5.w, a2[7]);
    }
    #pragma unroll
    for (int j = 0; j < 8; ++j) s_q[ul * RS + c0 + j] = a2[j];
  }
  __syncthreads();

  // ---- hidden = relu([gue | rep] @ Wu1 + bu1)  (thread: user ul, 16 cols)
  {
    const int c0 = tx * 16;
    float a3[16];
    #pragma unroll
    for (int j = 0; j < 4; ++j) {
      const float4 b4 = ((const float4*)(bu1 + c0))[j];
      a3[4*j]=b4.x; a3[4*j+1]=b4.y; a3[4*j+2]=b4.z; a3[4*j+3]=b4.w;
    }
    for (int s = 0; s < GCN; ++s) {
      const float x = s_gue[ul * RS + s];
      const float4* wp = (const float4*)(Wu1 + (size_t)s * HIDD + c0);
      #pragma unroll
      for (int j = 0; j < 4; ++j) {
        const float4 w4 = wp[j];
        a3[4*j]   = fmaf(x, w4.x, a3[4*j]);
        a3[4*j+1] = fmaf(x, w4.y, a3[4*j+1]);
        a3[4*j+2] = fmaf(x, w4.z, a3[4*j+2]);
        a3[4*j+3] = fmaf(x, w4.w, a3[4*j+3]);
      }
    }
    for (int s = 0; s < TD; ++s) {
      const float x = s_q[ul * RS + s];  // rep
      const float4* wp = (const float4*)(Wu1 + (size_t)(GCN + s) * HIDD + c0);
      #pragma unroll
      for (int j = 0; j < 4; ++j) {
        const float4 w4 = wp[j];
        a3[4*j]   = fmaf(x, w4.x, a3[4*j]);
        a3[4*j+1] = fmaf(x, w4.y, a3[4*j+1]);
        a3[4*j+2] = fmaf(x, w4.z, a3[4*j+2]);
        a3[4*j+3] = fmaf(x, w4.w, a3[4*j+3]);
      }
    }
    #pragma unroll
    for (int j = 0; j < 16; ++j) s_hid[ul * HS + c0 + j] = fmaxf(a3[j], 0.f);
  }
  __syncthreads();

  // ---- user_emb = normalize(hidden @ Wu2 + bu2)
  {
    const int c0 = tx * 8;
    float a4[8];
    {
      const float4 b4 = *(const float4*)(bu2 + c0);
      const float4 b5 = *(const float4*)(bu2 + c0 + 4);
      a4[0]=b4.x; a4[1]=b4.y; a4[2]=b4.z; a4[3]=b4.w;
      a4[4]=b5.x; a4[5]=b5.y; a4[6]=b5.z; a4[7]=b5.w;
    }
    for (int h = 0; h < HIDD; ++h) {
      const float x = s_hid[ul * HS + h];
      const float4 w4 = *(const float4*)(Wu2 + (size_t)h * TD + c0);
      const float4 w5 = *(const float4*)(Wu2 + (size_t)h * TD + c0 + 4);
      a4[0] = fmaf(x, w4.x, a4[0]); a4[1] = fmaf(x, w4.y, a4[1]);
      a4[2] = fmaf(x, w4.z, a4[2]); a4[3] = fmaf(x, w4.w, a4[3]);
      a4[4] = fmaf(x, w5.x, a4[4]); a4[5] = fmaf(x, w5.y, a4[5]);
      a4[6] = fmaf(x, w5.z, a4[6]); a4[7] = fmaf(x, w5.w, a4[7]);
    }
    float ssq = 0.f;
    #pragma unroll
    for (int j = 0; j < 8; ++j) ssq = fmaf(a4[j], a4[j], ssq);
    ssq += __shfl_xor(ssq, 1, 16);
    ssq += __shfl_xor(ssq, 2, 16);
    ssq += __shfl_xor(ssq, 4, 16);
    ssq += __shfl_xor(ssq, 8, 16);
    const float scale = 1.f / fmaxf(sqrtf(ssq), 1e-12f);
    float4* op = (float4*)(out + (size_t)(NITEMS + u0 + ul) * TD + c0);
    float4 o0, o1;
    o0.x=a4[0]*scale; o0.y=a4[1]*scale; o0.z=a4[2]*scale; o0.w=a4[3]*scale;
    o1.x=a4[4]*scale; o1.y=a4[5]*scale; o1.z=a4[6]*scale; o1.w=a4[7]*scale;
    op[0] = o0; op[1] = o1;
  }
}

extern "C" void kernel_launch(void* const* d_in, const int* in_sizes, int n_in,
                              void* d_out, int out_size, void* d_ws, size_t ws_size,
                              hipStream_t stream) {
  const float* item_feat = (const float*)d_in[0];
  const float* gcn_item  = (const float*)d_in[1];
  const float* gcn_user  = (const float*)d_in[2];
  const int*   user_items= (const int*)  d_in[3];
  const float* Wg  = (const float*)d_in[4];
  const float* bg  = (const float*)d_in[5];
  const float* Wi1 = (const float*)d_in[6];
  const float* bi1 = (const float*)d_in[7];
  const float* Wi2 = (const float*)d_in[8];
  const float* bi2 = (const float*)d_in[9];
  const float* Wq  = (const float*)d_in[10];
  const float* bq  = (const float*)d_in[11];
  const float* Wk  = (const float*)d_in[12];
  // d_in[13] = bk: provably softmax-invariant, dropped
  const float* Wu1 = (const float*)d_in[14];
  const float* bu1 = (const float*)d_in[15];
  const float* Wu2 = (const float*)d_in[16];
  const float* bu2 = (const float*)d_in[17];
  float* out = (float*)d_out;

  item_kernel<<<(NITEMS + TI - 1) / TI, 256, 0, stream>>>(
      item_feat, gcn_item, Wg, bg, Wi1, bi1, Wi2, bi2, out);
  user_kernel<<<NUSERS / UT, 256, 0, stream>>>(
      gcn_user, user_items, Wq, bq, Wk, Wu1, bu1, Wu2, bu2,
      out /*item_emb*/, out);
}

// Round 2
// 175.673 us; speedup vs baseline: 5.2747x; 5.2747x over previous
//
#include <hip/hip_runtime.h>
#include <hip/hip_bf16.h>
#include <math.h>

#define NITEMS 100000
#define NUSERS 16384
#define GCN 128
#define GEO 32
#define HIDD 256
#define TD 128
#define RK 50

typedef unsigned int uint;
typedef unsigned short ushort;
typedef __bf16 bf16x8 __attribute__((ext_vector_type(8)));
typedef float f32x4 __attribute__((ext_vector_type(4)));

__device__ __forceinline__ ushort bfb(float x) {
  union { __hip_bfloat16 b; ushort u; } t; t.b = __float2bfloat16(x); return t.u;
}
__device__ __forceinline__ uint packbf2(float a, float b) {
  return (uint)bfb(a) | ((uint)bfb(b) << 16);
}
__device__ __forceinline__ float bflo(uint d) { return __uint_as_float(d << 16); }
__device__ __forceinline__ float bfhi(uint d) { return __uint_as_float(d & 0xffff0000u); }

union U4B { uint4 u; bf16x8 b; };
__device__ __forceinline__ bf16x8 ldfrag(const ushort* p) { U4B t; t.u = *(const uint4*)p; return t.b; }

__device__ __forceinline__ void glds16(const void* g, void* l) {
  __builtin_amdgcn_global_load_lds((const __attribute__((address_space(1))) void*)g,
                                   (__attribute__((address_space(3))) void*)l, 16, 0, 0);
}
// 256 threads cooperatively DMA `bytes` (16B granular) global -> LDS, both linear.
__device__ __forceinline__ void stage_glds(const char* src, char* dst, int bytes, int tid) {
  for (int off = tid * 16; off < bytes; off += 4096) glds16(src + off, dst + off);
}

// ======================= weight prep (bf16 chunk-major, padded to 40) =======================
// W1P layout: [K/32][256 cols][40]  (k within chunk at [c*40 + (k&31)])
// W2P layout: [K/32][128 cols][40]
__global__ __launch_bounds__(256) void prep_convert(
    const float* __restrict__ Wi1, const float* __restrict__ Wi2,
    const float* __restrict__ Wu1, const float* __restrict__ Wu2,
    ushort* __restrict__ Wi1P, ushort* __restrict__ Wi2P,
    ushort* __restrict__ Wu1P, ushort* __restrict__ Wu2P)
{
  int id = blockIdx.x * 256 + threadIdx.x;
  if (id < 40960) {                       // Wi1 [160][256]
    int k = id >> 8, c = id & 255;
    Wi1P[(k >> 5) * 10240 + c * 40 + (k & 31)] = bfb(Wi1[id]);
  } else if (id < 73728) {                // Wi2 [256][128]
    int i = id - 40960; int k = i >> 7, c = i & 127;
    Wi2P[(k >> 5) * 5120 + c * 40 + (k & 31)] = bfb(Wi2[i]);
  } else if (id < 139264) {               // Wu1 [256][256]
    int i = id - 73728; int k = i >> 8, c = i & 255;
    Wu1P[(k >> 5) * 10240 + c * 40 + (k & 31)] = bfb(Wu1[i]);
  } else if (id < 172032) {               // Wu2 [256][128]
    int i = id - 139264; int k = i >> 7, c = i & 127;
    Wu2P[(k >> 5) * 5120 + c * 40 + (k & 31)] = bfb(Wu2[i]);
  }
}

// WqkS[g][s] = sum_t Wq[g,t]*Wk[s,t]; bqk[s] = sum_t bq[t]*Wk[s,t]
__global__ __launch_bounds__(256) void prep_wqk(
    const float* __restrict__ Wq, const float* __restrict__ Wk,
    const float* __restrict__ bq, float* __restrict__ WqkS, float* __restrict__ bqk)
{
  int id = blockIdx.x * 256 + threadIdx.x;
  if (id < 16384) {
    int g = id >> 7, s = id & 127;
    float acc = 0.f;
    for (int t = 0; t < 128; ++t) acc = fmaf(Wq[g * 128 + t], Wk[s * 128 + t], acc);
    WqkS[g * 128 + s] = acc;
  } else if (id < 16512) {
    int s = id - 16384;
    float acc = 0.f;
    for (int t = 0; t < 128; ++t) acc = fmaf(bq[t], Wk[s * 128 + t], acc);
    bqk[s] = acc;
  }
}

// ======================= fused MLP tower (MFMA bf16), item & user =======================
// 64 rows/block, 4 waves; GEMM1: [64xK1]@[K1x256] relu -> GEMM2: [64x256]@[256x128] -> L2 normalize.
template <int K1CH, bool ITEM>
__global__ __launch_bounds__(256) void mlp_kernel(
    const float* __restrict__ xmain,      // gcn_item / gcn_user
    const float* __restrict__ feat,       // item_feat / unused
    const float* __restrict__ Wg, const float* __restrict__ bg,
    const ushort* __restrict__ repB,      // unused for item
    const ushort* __restrict__ W1P, const float* __restrict__ b1,
    const ushort* __restrict__ W2P, const float* __restrict__ b2,
    float* __restrict__ outp, int M)
{
  __shared__ __align__(16) ushort s_a[64 * 264];      // A tile / hidden tile (bf16, stride 264)
  __shared__ __align__(16) ushort s_b[2][256 * 40];   // double-buffered weight chunks
  __shared__ float s_red[64 * 4];
  __shared__ float s_inv[64];

  const int tid = threadIdx.x;
  const int wid = tid >> 6, lane = tid & 63, g = lane >> 4, q = lane & 15;
  const int i0 = blockIdx.x * 64;

  // prefetch first GEMM1 weight chunk (overlaps A staging)
  stage_glds((const char*)W1P, (char*)s_b[0], 20480, tid);

  // ---- stage A tile as bf16
  if (ITEM) {
    #pragma unroll
    for (int r = 0; r < 8; ++r) {
      int lin = r * 256 + tid;
      int it = lin >> 5, c4 = (lin & 31) * 4;
      int row = i0 + it;
      float4 v = make_float4(0.f, 0.f, 0.f, 0.f);
      if (row < M) v = *(const float4*)(xmain + (size_t)row * GCN + c4);
      *(uint*)(&s_a[it * 264 + GEO + c4])     = packbf2(v.x, v.y);
      *(uint*)(&s_a[it * 264 + GEO + c4 + 2]) = packbf2(v.z, v.w);
    }
    #pragma unroll
    for (int r = 0; r < 8; ++r) {
      int lin = r * 256 + tid;
      int it = lin >> 5, gg = lin & 31;
      int row = i0 + it;
      float f0 = 0.f, f1 = 0.f;
      if (row < M) { f0 = feat[(size_t)row * 2]; f1 = feat[(size_t)row * 2 + 1]; }
      float val = fmaxf(fmaf(f0, Wg[gg], fmaf(f1, Wg[GEO + gg], bg[gg])), 0.f);
      s_a[it * 264 + gg] = bfb(val);
    }
  } else {
    #pragma unroll
    for (int r = 0; r < 8; ++r) {
      int lin = r * 256 + tid;
      int it = lin >> 5, c4 = (lin & 31) * 4;
      int row = i0 + it;
      float4 v = *(const float4*)(xmain + (size_t)row * GCN + c4);
      *(uint*)(&s_a[it * 264 + c4])     = packbf2(v.x, v.y);
      *(uint*)(&s_a[it * 264 + c4 + 2]) = packbf2(v.z, v.w);
    }
    #pragma unroll
    for (int r = 0; r < 4; ++r) {
      int lin = r * 256 + tid;
      int it = lin >> 4, c8 = (lin & 15) * 8;
      uint4 v = *(const uint4*)(repB + (size_t)(i0 + it) * TD + c8);
      *(uint4*)(&s_a[it * 264 + GCN + c8]) = v;
    }
  }

  // ---- GEMM1
  f32x4 acc[4][4];
  #pragma unroll
  for (int cf = 0; cf < 4; ++cf) {
    float bv = b1[wid * 64 + cf * 16 + q];
    f32x4 t = {bv, bv, bv, bv};
    #pragma unroll
    for (int rf = 0; rf < 4; ++rf) acc[rf][cf] = t;
  }

  for (int kb = 0; kb < K1CH; ++kb) {
    __syncthreads();   // chunk kb in LDS (sync drains vmcnt), prior reads of other buf done
    if (kb + 1 < K1CH)
      stage_glds((const char*)W1P + (kb + 1) * 20480, (char*)s_b[(kb + 1) & 1], 20480, tid);
    const ushort* bc = s_b[kb & 1];
    bf16x8 af[4], bfr[4];
    #pragma unroll
    for (int rf = 0; rf < 4; ++rf) af[rf] = ldfrag(&s_a[(16 * rf + q) * 264 + kb * 32 + g * 8]);
    #pragma unroll
    for (int cf = 0; cf < 4; ++cf) bfr[cf] = ldfrag(&bc[(wid * 64 + cf * 16 + q) * 40 + g * 8]);
    #pragma unroll
    for (int rf = 0; rf < 4; ++rf)
      #pragma unroll
      for (int cf = 0; cf < 4; ++cf)
        acc[rf][cf] = __builtin_amdgcn_mfma_f32_16x16x32_bf16(af[rf], bfr[cf], acc[rf][cf], 0, 0, 0);
  }
  __syncthreads();   // all A/B reads done; safe to overwrite s_a and s_b[0]

  // prefetch GEMM2 chunk 0; store relu(hidden) bf16 into s_a
  stage_glds((const char*)W2P, (char*)s_b[0], 10240, tid);
  #pragma unroll
  for (int rf = 0; rf < 4; ++rf)
    #pragma unroll
    for (int cf = 0; cf < 4; ++cf)
      #pragma unroll
      for (int e = 0; e < 4; ++e)
        s_a[(16 * rf + 4 * g + e) * 264 + wid * 64 + cf * 16 + q] = bfb(fmaxf(acc[rf][cf][e], 0.f));

  // ---- GEMM2
  f32x4 acc2[4][2];
  #pragma unroll
  for (int cf = 0; cf < 2; ++cf) {
    float bv = b2[wid * 32 + cf * 16 + q];
    f32x4 t = {bv, bv, bv, bv};
    #pragma unroll
    for (int rf = 0; rf < 4; ++rf) acc2[rf][cf] = t;
  }
  for (int kb = 0; kb < 8; ++kb) {
    __syncthreads();
    if (kb + 1 < 8)
      stage_glds((const char*)W2P + (kb + 1) * 10240, (char*)s_b[(kb + 1) & 1], 10240, tid);
    const ushort* bc = s_b[kb & 1];
    bf16x8 af[4], bf2[2];
    #pragma unroll
    for (int rf = 0; rf < 4; ++rf) af[rf] = ldfrag(&s_a[(16 * rf + q) * 264 + kb * 32 + g * 8]);
    #pragma unroll
    for (int cf = 0; cf < 2; ++cf) bf2[cf] = ldfrag(&bc[(wid * 32 + cf * 16 + q) * 40 + g * 8]);
    #pragma unroll
    for (int rf = 0; rf < 4; ++rf)
      #pragma unroll
      for (int cf = 0; cf < 2; ++cf)
        acc2[rf][cf] = __builtin_amdgcn_mfma_f32_16x16x32_bf16(af[rf], bf2[cf], acc2[rf][cf], 0, 0, 0);
  }

  // ---- row L2-norm + store
  #pragma unroll
  for (int rf = 0; rf < 4; ++rf) {
    #pragma unroll
    for (int e = 0; e < 4; ++e) {
      float p = acc2[rf][0][e] * acc2[rf][0][e] + acc2[rf][1][e] * acc2[rf][1][e];
      p += __shfl_xor(p, 1, 16); p += __shfl_xor(p, 2, 16);
      p += __shfl_xor(p, 4, 16); p += __shfl_xor(p, 8, 16);
      if (q == 0) s_red[(16 * rf + 4 * g + e) * 4 + wid] = p;
    }
  }
  __syncthreads();
  if (tid < 64) {
    float s = s_red[tid * 4] + s_red[tid * 4 + 1] + s_red[tid * 4 + 2] + s_red[tid * 4 + 3];
    s_inv[tid] = 1.f / fmaxf(sqrtf(s), 1e-12f);
  }
  __syncthreads();
  #pragma unroll
  for (int rf = 0; rf < 4; ++rf) {
    #pragma unroll
    for (int e = 0; e < 4; ++e) {
      int row = 16 * rf + 4 * g + e;
      int grow = i0 + row;
      if (grow < M) {
        float sc = s_inv[row];
        #pragma unroll
        for (int cf = 0; cf < 2; ++cf)
          outp[(size_t)grow * TD + wid * 32 + cf * 16 + q] = acc2[rf][cf][e] * sc;
      }
    }
  }
}

// ======================= qt = gue @ WqkS + bqk =======================
__global__ __launch_bounds__(256) void qt_kernel(
    const float* __restrict__ gcn_user, const float* __restrict__ WqkS,
    const float* __restrict__ bqk, float* __restrict__ qt)
{
  __shared__ float s_gue[16 * 132];
  const int tid = threadIdx.x;
  const int u0 = blockIdx.x * 16;
  #pragma unroll
  for (int r = 0; r < 8; ++r) {
    int lin = r * 256 + tid;
    int u = lin >> 7, c = lin & 127;
    s_gue[u * 132 + c] = gcn_user[(size_t)(u0 + u) * GCN + c];
  }
  __syncthreads();
  const int ul = tid >> 4, tx = tid & 15, c0 = tx * 8;
  float a[8];
  { float4 b4 = *(const float4*)(bqk + c0); float4 b5 = *(const float4*)(bqk + c0 + 4);
    a[0]=b4.x; a[1]=b4.y; a[2]=b4.z; a[3]=b4.w; a[4]=b5.x; a[5]=b5.y; a[6]=b5.z; a[7]=b5.w; }
  for (int g = 0; g < 128; ++g) {
    float x = s_gue[ul * 132 + g];
    float4 w4 = *(const float4*)(WqkS + g * 128 + c0);
    float4 w5 = *(const float4*)(WqkS + g * 128 + c0 + 4);
    a[0] = fmaf(x, w4.x, a[0]); a[1] = fmaf(x, w4.y, a[1]);
    a[2] = fmaf(x, w4.z, a[2]); a[3] = fmaf(x, w4.w, a[3]);
    a[4] = fmaf(x, w5.x, a[4]); a[5] = fmaf(x, w5.y, a[5]);
    a[6] = fmaf(x, w5.z, a[6]); a[7] = fmaf(x, w5.w, a[7]);
  }
  float* op = qt + (size_t)(u0 + ul) * TD + c0;
  *(float4*)op = make_float4(a[0], a[1], a[2], a[3]);
  *(float4*)(op + 4) = make_float4(a[4], a[5], a[6], a[7]);
}

// ======================= item_emb f32 -> bf16 copy (for the gather) =======================
__global__ __launch_bounds__(256) void bf16copy(const float* __restrict__ src, ushort* __restrict__ dst) {
  size_t base = ((size_t)blockIdx.x * 256 + threadIdx.x) * 8;
  if (base < (size_t)NITEMS * TD) {
    float4 v0 = *(const float4*)(src + base), v1 = *(const float4*)(src + base + 4);
    uint4 o;
    o.x = packbf2(v0.x, v0.y); o.y = packbf2(v0.z, v0.w);
    o.z = packbf2(v1.x, v1.y); o.w = packbf2(v1.z, v1.w);
    *(uint4*)(dst + base) = o;
  }
}

// ======================= attention: one wave per user, single-pass =======================
// scores[j] = h_j . qt (bk dropped: softmax-invariant); H kept in registers.
__global__ __launch_bounds__(256) void attn_kernel(
    const int* __restrict__ user_items, const float* __restrict__ qt,
    const ushort* __restrict__ itemB, ushort* __restrict__ repB)
{
  __shared__ int s_idx[4][52];
  const int tid = threadIdx.x;
  const int wid = tid >> 6, lane = tid & 63, g = lane >> 4, q = lane & 15;
  const int u = blockIdx.x * 4 + wid;
  const int c0 = q * 8;

  if (lane < 52) s_idx[wid][lane] = (lane < 50) ? user_items[(size_t)u * RK + lane] : 0;
  float qv[8];
  { float4 a = *(const float4*)(qt + (size_t)u * TD + c0);
    float4 b = *(const float4*)(qt + (size_t)u * TD + c0 + 4);
    qv[0]=a.x; qv[1]=a.y; qv[2]=a.z; qv[3]=a.w; qv[4]=b.x; qv[5]=b.y; qv[6]=b.z; qv[7]=b.w; }
  __syncthreads();

  uint4 h[13]; float sc[13];
  #pragma unroll
  for (int i = 0; i < 13; ++i) {
    int j = 4 * i + g;                 // lane-group g handles rows j = 4i+g
    int idx = s_idx[wid][j];
    h[i] = *(const uint4*)(itemB + (size_t)idx * TD + c0);
    float p = bflo(h[i].x) * qv[0] + bfhi(h[i].x) * qv[1]
            + bflo(h[i].y) * qv[2] + bfhi(h[i].y) * qv[3]
            + bflo(h[i].z) * qv[4] + bfhi(h[i].z) * qv[5]
            + bflo(h[i].w) * qv[6] + bfhi(h[i].w) * qv[7];
    p += __shfl_xor(p, 1, 16); p += __shfl_xor(p, 2, 16);
    p += __shfl_xor(p, 4, 16); p += __shfl_xor(p, 8, 16);
    sc[i] = (j < RK) ? p : -3.0e38f;
  }
  float m = sc[0];
  #pragma unroll
  for (int i = 1; i < 13; ++i) m = fmaxf(m, sc[i]);
  m = fmaxf(m, __shfl_xor(m, 16, 64));
  m = fmaxf(m, __shfl_xor(m, 32, 64));
  float ssum = 0.f;
  #pragma unroll
  for (int i = 0; i < 13; ++i) { sc[i] = __expf(sc[i] - m); ssum += sc[i]; }
  ssum += __shfl_xor(ssum, 16, 64);
  ssum += __shfl_xor(ssum, 32, 64);
  const float inv = 1.f / ssum;
  float rep[8] = {0, 0, 0, 0, 0, 0, 0, 0};
  #pragma unroll
  for (int i = 0; i < 13; ++i) {
    float a = sc[i] * inv;
    rep[0] = fmaf(a, bflo(h[i].x), rep[0]); rep[1] = fmaf(a, bfhi(h[i].x), rep[1]);
    rep[2] = fmaf(a, bflo(h[i].y), rep[2]); rep[3] = fmaf(a, bfhi(h[i].y), rep[3]);
    rep[4] = fmaf(a, bflo(h[i].z), rep[4]); rep[5] = fmaf(a, bfhi(h[i].z), rep[5]);
    rep[6] = fmaf(a, bflo(h[i].w), rep[6]); rep[7] = fmaf(a, bfhi(h[i].w), rep[7]);
  }
  #pragma unroll
  for (int c = 0; c < 8; ++c) {
    rep[c] += __shfl_xor(rep[c], 16, 64);
    rep[c] += __shfl_xor(rep[c], 32, 64);
  }
  if (g == 0) {
    uint4 o;
    o.x = packbf2(rep[0], rep[1]); o.y = packbf2(rep[2], rep[3]);
    o.z = packbf2(rep[4], rep[5]); o.w = packbf2(rep[6], rep[7]);
    *(uint4*)(repB + (size_t)u * TD + c0) = o;
  }
}

extern "C" void kernel_launch(void* const* d_in, const int* in_sizes, int n_in,
                              void* d_out, int out_size, void* d_ws, size_t ws_size,
                              hipStream_t stream) {
  const float* item_feat  = (const float*)d_in[0];
  const float* gcn_item   = (const float*)d_in[1];
  const float* gcn_user   = (const float*)d_in[2];
  const int*   user_items = (const int*)  d_in[3];
  const float* Wg  = (const float*)d_in[4];
  const float* bg  = (const float*)d_in[5];
  const float* Wi1 = (const float*)d_in[6];
  const float* bi1 = (const float*)d_in[7];
  const float* Wi2 = (const float*)d_in[8];
  const float* bi2 = (const float*)d_in[9];
  const float* Wq  = (const float*)d_in[10];
  const float* bq  = (const float*)d_in[11];
  const float* Wk  = (const float*)d_in[12];
  // d_in[13] = bk: softmax-invariant, dropped
  const float* Wu1 = (const float*)d_in[14];
  const float* bu1 = (const float*)d_in[15];
  const float* Wu2 = (const float*)d_in[16];
  const float* bu2 = (const float*)d_in[17];
  float* out = (float*)d_out;

  // workspace layout (bytes): total ~38.7 MB
  char* ws = (char*)d_ws;
  ushort* Wi1P  = (ushort*)(ws + 0);         //  5*256*40*2 = 102400
  ushort* Wi2P  = (ushort*)(ws + 102400);    //  8*128*40*2 =  81920
  ushort* Wu1P  = (ushort*)(ws + 184320);    //  8*256*40*2 = 163840
  ushort* Wu2P  = (ushort*)(ws + 348160);    //  8*128*40*2 =  81920
  float*  WqkS  = (float*) (ws + 430080);    //  128*128*4  =  65536
  float*  bqk   = (float*) (ws + 495616);    //  128*4      =    512
  float*  qtb   = (float*) (ws + 496128);    //  16384*128*4 = 8388608
  ushort* itemB = (ushort*)(ws + 8884736);   //  100000*128*2 = 25600000
  ushort* repB  = (ushort*)(ws + 34484736);  //  16384*128*2 = 4194304

  prep_convert<<<672, 256, 0, stream>>>(Wi1, Wi2, Wu1, Wu2, Wi1P, Wi2P, Wu1P, Wu2P);
  prep_wqk<<<65, 256, 0, stream>>>(Wq, Wk, bq, WqkS, bqk);
  qt_kernel<<<NUSERS / 16, 256, 0, stream>>>(gcn_user, WqkS, bqk, qtb);
  mlp_kernel<5, true><<<(NITEMS + 63) / 64, 256, 0, stream>>>(
      gcn_item, item_feat, Wg, bg, nullptr, Wi1P, bi1, Wi2P, bi2, out, NITEMS);
  bf16copy<<<(NITEMS * TD / 8 + 255) / 256, 256, 0, stream>>>(out, itemB);
  attn_kernel<<<NUSERS / 4, 256, 0, stream>>>(user_items, qtb, itemB, repB);
  mlp_kernel<8, false><<<NUSERS / 64, 256, 0, stream>>>(
      gcn_user, nullptr, Wg, bg, repB, Wu1P, bu1, Wu2P, bu2, out + (size_t)NITEMS * TD, NUSERS);
}

// Round 3
// 144.489 us; speedup vs baseline: 6.4131x; 1.2158x over previous
//
#include <hip/hip_runtime.h>
#include <hip/hip_bf16.h>
#include <math.h>

#define NITEMS 100000
#define NUSERS 16384
#define GCN 128
#define GEO 32
#define HIDD 256
#define TD 128
#define RK 50

typedef unsigned int uint;
typedef unsigned short ushort;
typedef __bf16 bf16x8 __attribute__((ext_vector_type(8)));
typedef float f32x4 __attribute__((ext_vector_type(4)));

__device__ __forceinline__ ushort bfb(float x) {
  union { __hip_bfloat16 b; ushort u; } t; t.b = __float2bfloat16(x); return t.u;
}
__device__ __forceinline__ uint packbf2(float a, float b) {
  return (uint)bfb(a) | ((uint)bfb(b) << 16);
}
__device__ __forceinline__ float bflo(uint d) { return __uint_as_float(d << 16); }
__device__ __forceinline__ float bfhi(uint d) { return __uint_as_float(d & 0xffff0000u); }

union U4B { uint4 u; bf16x8 b; };
__device__ __forceinline__ bf16x8 ldfrag(const ushort* p) { U4B t; t.u = *(const uint4*)p; return t.b; }

// ======================= weight prep: bf16, dense chunk-major [K/32][N][32] =======================
__global__ __launch_bounds__(256) void prep_convert(
    const float* __restrict__ Wi1, const float* __restrict__ Wi2,
    const float* __restrict__ Wu1, const float* __restrict__ Wu2,
    ushort* __restrict__ Wi1P, ushort* __restrict__ Wi2P,
    ushort* __restrict__ Wu1P, ushort* __restrict__ Wu2P)
{
  int id = blockIdx.x * 256 + threadIdx.x;
  if (id < 40960) {                       // Wi1 [160][256]
    int k = id >> 8, c = id & 255;
    Wi1P[(k >> 5) * 8192 + c * 32 + (k & 31)] = bfb(Wi1[id]);
  } else if (id < 73728) {                // Wi2 [256][128]
    int i = id - 40960; int k = i >> 7, c = i & 127;
    Wi2P[(k >> 5) * 4096 + c * 32 + (k & 31)] = bfb(Wi2[i]);
  } else if (id < 139264) {               // Wu1 [256][256]
    int i = id - 73728; int k = i >> 8, c = i & 255;
    Wu1P[(k >> 5) * 8192 + c * 32 + (k & 31)] = bfb(Wu1[i]);
  } else if (id < 172032) {               // Wu2 [256][128]
    int i = id - 139264; int k = i >> 7, c = i & 127;
    Wu2P[(k >> 5) * 4096 + c * 32 + (k & 31)] = bfb(Wu2[i]);
  }
}

// WqkS[g][s] = sum_t Wq[g,t]*Wk[s,t]; bqk[s] = sum_t bq[t]*Wk[s,t]
__global__ __launch_bounds__(256) void prep_wqk(
    const float* __restrict__ Wq, const float* __restrict__ Wk,
    const float* __restrict__ bq, float* __restrict__ WqkS, float* __restrict__ bqk)
{
  int id = blockIdx.x * 256 + threadIdx.x;
  if (id < 16384) {
    int g = id >> 7, s = id & 127;
    float acc = 0.f;
    for (int t = 0; t < 128; ++t) acc = fmaf(Wq[g * 128 + t], Wk[s * 128 + t], acc);
    WqkS[g * 128 + s] = acc;
  } else if (id < 16512) {
    int s = id - 16384;
    float acc = 0.f;
    for (int t = 0; t < 128; ++t) acc = fmaf(bq[t], Wk[s * 128 + t], acc);
    bqk[s] = acc;
  }
}

// ======================= fused MLP tower (MFMA bf16), item & user =======================
// 64 rows/block, 4 waves. B-fragments load DIRECTLY from global (L2-hot dense
// [K/32][N][32] layout) -> no weight LDS, no per-chunk barriers. Only A/hidden
// tile lives in LDS (34 KB -> 4 blocks/CU).
template <int K1, bool ITEM>
__global__ __launch_bounds__(256, 4) void mlp_kernel(
    const float* __restrict__ xmain,      // gcn_item / gcn_user
    const float* __restrict__ feat,       // item_feat / unused
    const float* __restrict__ Wg, const float* __restrict__ bg,
    const ushort* __restrict__ repB,      // unused for item
    const ushort* __restrict__ W1P, const float* __restrict__ b1,
    const ushort* __restrict__ W2P, const float* __restrict__ b2,
    float* __restrict__ outp, ushort* __restrict__ outb, int M)
{
  constexpr int ASTR = ITEM ? 168 : 264;   // GEMM1 A stride (2-way bank aliasing max)
  constexpr int K1CH = K1 / 32;
  __shared__ __align__(16) ushort s_a[64 * 264];   // A tile, then hidden tile
  __shared__ float s_red[64 * 4];
  __shared__ float s_inv[64];

  const int tid = threadIdx.x;
  const int wid = tid >> 6, lane = tid & 63, g = lane >> 4, q = lane & 15;
  const int i0 = blockIdx.x * 64;

  // ---- stage A tile as bf16 (coalesced f32 reads, converted in-register)
  if (ITEM) {
    #pragma unroll
    for (int r = 0; r < 8; ++r) {
      int lin = r * 256 + tid;
      int it = lin >> 5, c4 = (lin & 31) * 4;
      int row = i0 + it;
      float4 v = make_float4(0.f, 0.f, 0.f, 0.f);
      if (row < M) v = *(const float4*)(xmain + (size_t)row * GCN + c4);
      *(uint*)(&s_a[it * ASTR + GEO + c4])     = packbf2(v.x, v.y);
      *(uint*)(&s_a[it * ASTR + GEO + c4 + 2]) = packbf2(v.z, v.w);
    }
    #pragma unroll
    for (int r = 0; r < 8; ++r) {
      int lin = r * 256 + tid;
      int it = lin >> 5, gg = lin & 31;
      int row = i0 + it;
      float f0 = 0.f, f1 = 0.f;
      if (row < M) { f0 = feat[(size_t)row * 2]; f1 = feat[(size_t)row * 2 + 1]; }
      s_a[it * ASTR + gg] = bfb(fmaxf(fmaf(f0, Wg[gg], fmaf(f1, Wg[GEO + gg], bg[gg])), 0.f));
    }
  } else {
    #pragma unroll
    for (int r = 0; r < 8; ++r) {
      int lin = r * 256 + tid;
      int it = lin >> 5, c4 = (lin & 31) * 4;
      float4 v = *(const float4*)(xmain + (size_t)(i0 + it) * GCN + c4);
      *(uint*)(&s_a[it * ASTR + c4])     = packbf2(v.x, v.y);
      *(uint*)(&s_a[it * ASTR + c4 + 2]) = packbf2(v.z, v.w);
    }
    #pragma unroll
    for (int r = 0; r < 4; ++r) {
      int lin = r * 256 + tid;
      int it = lin >> 4, c8 = (lin & 15) * 8;
      *(uint4*)(&s_a[it * ASTR + GCN + c8]) = *(const uint4*)(repB + (size_t)(i0 + it) * TD + c8);
    }
  }
  __syncthreads();

  // ---- GEMM1: [64 x K1] @ [K1 x 256], barrier-free K loop
  f32x4 acc[4][4];
  #pragma unroll
  for (int cf = 0; cf < 4; ++cf) {
    float bv = b1[wid * 64 + cf * 16 + q];
    f32x4 t = {bv, bv, bv, bv};
    #pragma unroll
    for (int rf = 0; rf < 4; ++rf) acc[rf][cf] = t;
  }
  {
    const ushort* bbase = W1P + (wid * 64 + q) * 32 + g * 8;
    #pragma unroll
    for (int kb = 0; kb < K1CH; ++kb) {
      bf16x8 af[4], bfr[4];
      #pragma unroll
      for (int rf = 0; rf < 4; ++rf) af[rf] = ldfrag(&s_a[(16 * rf + q) * ASTR + kb * 32 + g * 8]);
      #pragma unroll
      for (int cf = 0; cf < 4; ++cf) bfr[cf] = ldfrag(bbase + kb * 8192 + cf * 512);
      #pragma unroll
      for (int rf = 0; rf < 4; ++rf)
        #pragma unroll
        for (int cf = 0; cf < 4; ++cf)
          acc[rf][cf] = __builtin_amdgcn_mfma_f32_16x16x32_bf16(af[rf], bfr[cf], acc[rf][cf], 0, 0, 0);
    }
  }
  __syncthreads();   // all A reads done; safe to overwrite s_a with hidden

  // ---- relu(hidden) -> s_a (stride 264), shfl-paired 4B stores (bank-conflict-free-ish)
  #pragma unroll
  for (int rf = 0; rf < 4; ++rf)
    #pragma unroll
    for (int cf = 0; cf < 4; ++cf)
      #pragma unroll
      for (int e = 0; e < 4; ++e) {
        float v = fmaxf(acc[rf][cf][e], 0.f);
        float vp = __shfl_xor(v, 1);
        if (!(q & 1))
          *(uint*)(&s_a[(16 * rf + 4 * g + e) * 264 + wid * 64 + cf * 16 + q]) = packbf2(v, vp);
      }
  __syncthreads();

  // ---- GEMM2: [64 x 256] @ [256 x 128], barrier-free K loop
  f32x4 acc2[4][2];
  #pragma unroll
  for (int cf = 0; cf < 2; ++cf) {
    float bv = b2[wid * 32 + cf * 16 + q];
    f32x4 t = {bv, bv, bv, bv};
    #pragma unroll
    for (int rf = 0; rf < 4; ++rf) acc2[rf][cf] = t;
  }
  {
    const ushort* bbase = W2P + (wid * 32 + q) * 32 + g * 8;
    #pragma unroll
    for (int kb = 0; kb < 8; ++kb) {
      bf16x8 af[4], bf2[2];
      #pragma unroll
      for (int rf = 0; rf < 4; ++rf) af[rf] = ldfrag(&s_a[(16 * rf + q) * 264 + kb * 32 + g * 8]);
      #pragma unroll
      for (int cf = 0; cf < 2; ++cf) bf2[cf] = ldfrag(bbase + kb * 4096 + cf * 512);
      #pragma unroll
      for (int rf = 0; rf < 4; ++rf)
        #pragma unroll
        for (int cf = 0; cf < 2; ++cf)
          acc2[rf][cf] = __builtin_amdgcn_mfma_f32_16x16x32_bf16(af[rf], bf2[cf], acc2[rf][cf], 0, 0, 0);
    }
  }

  // ---- row L2-norm
  #pragma unroll
  for (int rf = 0; rf < 4; ++rf) {
    #pragma unroll
    for (int e = 0; e < 4; ++e) {
      float p = acc2[rf][0][e] * acc2[rf][0][e] + acc2[rf][1][e] * acc2[rf][1][e];
      p += __shfl_xor(p, 1, 16); p += __shfl_xor(p, 2, 16);
      p += __shfl_xor(p, 4, 16); p += __shfl_xor(p, 8, 16);
      if (q == 0) s_red[(16 * rf + 4 * g + e) * 4 + wid] = p;
    }
  }
  __syncthreads();
  if (tid < 64) {
    float s = s_red[tid * 4] + s_red[tid * 4 + 1] + s_red[tid * 4 + 2] + s_red[tid * 4 + 3];
    s_inv[tid] = 1.f / fmaxf(sqrtf(s), 1e-12f);
  }
  __syncthreads();

  // ---- store f32 out (+ bf16 copy for the gather, item only)
  #pragma unroll
  for (int rf = 0; rf < 4; ++rf) {
    #pragma unroll
    for (int e = 0; e < 4; ++e) {
      int row = 16 * rf + 4 * g + e;
      int grow = i0 + row;
      if (grow < M) {
        float sc = s_inv[row];
        #pragma unroll
        for (int cf = 0; cf < 2; ++cf) {
          float v = acc2[rf][cf][e] * sc;
          outp[(size_t)grow * TD + wid * 32 + cf * 16 + q] = v;
          if (ITEM) outb[(size_t)grow * TD + wid * 32 + cf * 16 + q] = bfb(v);
        }
      }
    }
  }
}

// ======================= qt = gue @ WqkS + bqk =======================
__global__ __launch_bounds__(256) void qt_kernel(
    const float* __restrict__ gcn_user, const float* __restrict__ WqkS,
    const float* __restrict__ bqk, float* __restrict__ qt)
{
  __shared__ float s_gue[16 * 132];
  const int tid = threadIdx.x;
  const int u0 = blockIdx.x * 16;
  #pragma unroll
  for (int r = 0; r < 8; ++r) {
    int lin = r * 256 + tid;
    int u = lin >> 7, c = lin & 127;
    s_gue[u * 132 + c] = gcn_user[(size_t)(u0 + u) * GCN + c];
  }
  __syncthreads();
  const int ul = tid >> 4, tx = tid & 15, c0 = tx * 8;
  float a[8];
  { float4 b4 = *(const float4*)(bqk + c0); float4 b5 = *(const float4*)(bqk + c0 + 4);
    a[0]=b4.x; a[1]=b4.y; a[2]=b4.z; a[3]=b4.w; a[4]=b5.x; a[5]=b5.y; a[6]=b5.z; a[7]=b5.w; }
  for (int g = 0; g < 128; ++g) {
    float x = s_gue[ul * 132 + g];
    float4 w4 = *(const float4*)(WqkS + g * 128 + c0);
    float4 w5 = *(const float4*)(WqkS + g * 128 + c0 + 4);
    a[0] = fmaf(x, w4.x, a[0]); a[1] = fmaf(x, w4.y, a[1]);
    a[2] = fmaf(x, w4.z, a[2]); a[3] = fmaf(x, w4.w, a[3]);
    a[4] = fmaf(x, w5.x, a[4]); a[5] = fmaf(x, w5.y, a[5]);
    a[6] = fmaf(x, w5.z, a[6]); a[7] = fmaf(x, w5.w, a[7]);
  }
  float* op = qt + (size_t)(u0 + ul) * TD + c0;
  *(float4*)op = make_float4(a[0], a[1], a[2], a[3]);
  *(float4*)(op + 4) = make_float4(a[4], a[5], a[6], a[7]);
}

// ======================= attention: one wave per user, single-pass =======================
__global__ __launch_bounds__(256) void attn_kernel(
    const int* __restrict__ user_items, const float* __restrict__ qt,
    const ushort* __restrict__ itemB, ushort* __restrict__ repB)
{
  __shared__ int s_idx[4][52];
  const int tid = threadIdx.x;
  const int wid = tid >> 6, lane = tid & 63, g = lane >> 4, q = lane & 15;
  const int u = blockIdx.x * 4 + wid;
  const int c0 = q * 8;

  if (lane < 52) s_idx[wid][lane] = (lane < 50) ? user_items[(size_t)u * RK + lane] : 0;
  float qv[8];
  { float4 a = *(const float4*)(qt + (size_t)u * TD + c0);
    float4 b = *(const float4*)(qt + (size_t)u * TD + c0 + 4);
    qv[0]=a.x; qv[1]=a.y; qv[2]=a.z; qv[3]=a.w; qv[4]=b.x; qv[5]=b.y; qv[6]=b.z; qv[7]=b.w; }
  __syncthreads();

  uint4 h[13]; float sc[13];
  #pragma unroll
  for (int i = 0; i < 13; ++i) {
    int j = 4 * i + g;
    int idx = s_idx[wid][j];
    h[i] = *(const uint4*)(itemB + (size_t)idx * TD + c0);
    float p = bflo(h[i].x) * qv[0] + bfhi(h[i].x) * qv[1]
            + bflo(h[i].y) * qv[2] + bfhi(h[i].y) * qv[3]
            + bflo(h[i].z) * qv[4] + bfhi(h[i].z) * qv[5]
            + bflo(h[i].w) * qv[6] + bfhi(h[i].w) * qv[7];
    p += __shfl_xor(p, 1, 16); p += __shfl_xor(p, 2, 16);
    p += __shfl_xor(p, 4, 16); p += __shfl_xor(p, 8, 16);
    sc[i] = (j < RK) ? p : -3.0e38f;
  }
  float m = sc[0];
  #pragma unroll
  for (int i = 1; i < 13; ++i) m = fmaxf(m, sc[i]);
  m = fmaxf(m, __shfl_xor(m, 16, 64));
  m = fmaxf(m, __shfl_xor(m, 32, 64));
  float ssum = 0.f;
  #pragma unroll
  for (int i = 0; i < 13; ++i) { sc[i] = __expf(sc[i] - m); ssum += sc[i]; }
  ssum += __shfl_xor(ssum, 16, 64);
  ssum += __shfl_xor(ssum, 32, 64);
  const float inv = 1.f / ssum;
  float rep[8] = {0, 0, 0, 0, 0, 0, 0, 0};
  #pragma unroll
  for (int i = 0; i < 13; ++i) {
    float a = sc[i] * inv;
    rep[0] = fmaf(a, bflo(h[i].x), rep[0]); rep[1] = fmaf(a, bfhi(h[i].x), rep[1]);
    rep[2] = fmaf(a, bflo(h[i].y), rep[2]); rep[3] = fmaf(a, bfhi(h[i].y), rep[3]);
    rep[4] = fmaf(a, bflo(h[i].z), rep[4]); rep[5] = fmaf(a, bfhi(h[i].z), rep[5]);
    rep[6] = fmaf(a, bflo(h[i].w), rep[6]); rep[7] = fmaf(a, bfhi(h[i].w), rep[7]);
  }
  #pragma unroll
  for (int c = 0; c < 8; ++c) {
    rep[c] += __shfl_xor(rep[c], 16, 64);
    rep[c] += __shfl_xor(rep[c], 32, 64);
  }
  if (g == 0) {
    uint4 o;
    o.x = packbf2(rep[0], rep[1]); o.y = packbf2(rep[2], rep[3]);
    o.z = packbf2(rep[4], rep[5]); o.w = packbf2(rep[6], rep[7]);
    *(uint4*)(repB + (size_t)u * TD + c0) = o;
  }
}

extern "C" void kernel_launch(void* const* d_in, const int* in_sizes, int n_in,
                              void* d_out, int out_size, void* d_ws, size_t ws_size,
                              hipStream_t stream) {
  const float* item_feat  = (const float*)d_in[0];
  const float* gcn_item   = (const float*)d_in[1];
  const float* gcn_user   = (const float*)d_in[2];
  const int*   user_items = (const int*)  d_in[3];
  const float* Wg  = (const float*)d_in[4];
  const float* bg  = (const float*)d_in[5];
  const float* Wi1 = (const float*)d_in[6];
  const float* bi1 = (const float*)d_in[7];
  const float* Wi2 = (const float*)d_in[8];
  const float* bi2 = (const float*)d_in[9];
  const float* Wq  = (const float*)d_in[10];
  const float* bq  = (const float*)d_in[11];
  const float* Wk  = (const float*)d_in[12];
  // d_in[13] = bk: softmax-invariant, dropped
  const float* Wu1 = (const float*)d_in[14];
  const float* bu1 = (const float*)d_in[15];
  const float* Wu2 = (const float*)d_in[16];
  const float* bu2 = (const float*)d_in[17];
  float* out = (float*)d_out;

  // workspace layout (bytes): ~34.3 MB total
  char* ws = (char*)d_ws;
  ushort* Wi1P  = (ushort*)(ws + 0);         // 5*256*32*2  =  81920
  ushort* Wi2P  = (ushort*)(ws + 81920);     // 8*128*32*2  =  65536
  ushort* Wu1P  = (ushort*)(ws + 147456);    // 8*256*32*2  = 131072
  ushort* Wu2P  = (ushort*)(ws + 278528);    // 8*128*32*2  =  65536
  float*  WqkS  = (float*) (ws + 344064);    // 128*128*4   =  65536
  float*  bqk   = (float*) (ws + 409600);    // 128*4       =    512
  float*  qtb   = (float*) (ws + 410112);    // 16384*128*4 = 8388608
  ushort* itemB = (ushort*)(ws + 8798720);   // 100000*128*2 = 25600000
  ushort* repB  = (ushort*)(ws + 34398720);  // 16384*128*2 = 4194304

  prep_convert<<<672, 256, 0, stream>>>(Wi1, Wi2, Wu1, Wu2, Wi1P, Wi2P, Wu1P, Wu2P);
  prep_wqk<<<65, 256, 0, stream>>>(Wq, Wk, bq, WqkS, bqk);
  qt_kernel<<<NUSERS / 16, 256, 0, stream>>>(gcn_user, WqkS, bqk, qtb);
  mlp_kernel<160, true><<<(NITEMS + 63) / 64, 256, 0, stream>>>(
      gcn_item, item_feat, Wg, bg, nullptr, Wi1P, bi1, Wi2P, bi2, out, itemB, NITEMS);
  attn_kernel<<<NUSERS / 4, 256, 0, stream>>>(user_items, qtb, itemB, repB);
  mlp_kernel<256, false><<<NUSERS / 64, 256, 0, stream>>>(
      gcn_user, nullptr, Wg, bg, repB, Wu1P, bu1, Wu2P, bu2, out + (size_t)NITEMS * TD, nullptr, NUSERS);
}

// Round 4
// 137.563 us; speedup vs baseline: 6.7361x; 1.0504x over previous
//
#include <hip/hip_runtime.h>
#include <hip/hip_bf16.h>
#include <math.h>

#define NITEMS 100000
#define NUSERS 16384
#define GCN 128
#define GEO 32
#define HIDD 256
#define TD 128
#define RK 50

typedef unsigned int uint;
typedef unsigned short ushort;
typedef __bf16 bf16x8 __attribute__((ext_vector_type(8)));
typedef float f32x4 __attribute__((ext_vector_type(4)));

__device__ __forceinline__ ushort bfb(float x) {
  union { __hip_bfloat16 b; ushort u; } t; t.b = __float2bfloat16(x); return t.u;
}
__device__ __forceinline__ uint packbf2(float a, float b) {
  return (uint)bfb(a) | ((uint)bfb(b) << 16);
}
__device__ __forceinline__ float bflo(uint d) { return __uint_as_float(d << 16); }
__device__ __forceinline__ float bfhi(uint d) { return __uint_as_float(d & 0xffff0000u); }

union U4B { uint4 u; bf16x8 b; };
__device__ __forceinline__ bf16x8 ldfrag(const ushort* p) { U4B t; t.u = *(const uint4*)p; return t.b; }

// ======================= weight prep: bf16, dense chunk-major [K/32][N][32] =======================
__global__ __launch_bounds__(256) void prep_convert(
    const float* __restrict__ Wi1, const float* __restrict__ Wi2,
    const float* __restrict__ Wu1, const float* __restrict__ Wu2,
    ushort* __restrict__ Wi1P, ushort* __restrict__ Wi2P,
    ushort* __restrict__ Wu1P, ushort* __restrict__ Wu2P)
{
  int id = blockIdx.x * 256 + threadIdx.x;
  if (id < 40960) {                       // Wi1 [160][256]
    int k = id >> 8, c = id & 255;
    Wi1P[(k >> 5) * 8192 + c * 32 + (k & 31)] = bfb(Wi1[id]);
  } else if (id < 73728) {                // Wi2 [256][128]
    int i = id - 40960; int k = i >> 7, c = i & 127;
    Wi2P[(k >> 5) * 4096 + c * 32 + (k & 31)] = bfb(Wi2[i]);
  } else if (id < 139264) {               // Wu1 [256][256]
    int i = id - 73728; int k = i >> 8, c = i & 255;
    Wu1P[(k >> 5) * 8192 + c * 32 + (k & 31)] = bfb(Wu1[i]);
  } else if (id < 172032) {               // Wu2 [256][128]
    int i = id - 139264; int k = i >> 7, c = i & 127;
    Wu2P[(k >> 5) * 4096 + c * 32 + (k & 31)] = bfb(Wu2[i]);
  }
}

// WqkS[g][s] = sum_t Wq[g,t]*Wk[s,t]; bqk[s] = sum_t bq[t]*Wk[s,t]
__global__ __launch_bounds__(256) void prep_wqk(
    const float* __restrict__ Wq, const float* __restrict__ Wk,
    const float* __restrict__ bq, float* __restrict__ WqkS, float* __restrict__ bqk)
{
  int id = blockIdx.x * 256 + threadIdx.x;
  if (id < 16384) {
    int g = id >> 7, s = id & 127;
    float acc = 0.f;
    for (int t = 0; t < 128; t += 4) {
      float4 a = *(const float4*)(Wq + g * 128 + t);
      float4 b = *(const float4*)(Wk + s * 128 + t);
      acc += a.x * b.x + a.y * b.y + a.z * b.z + a.w * b.w;
    }
    WqkS[g * 128 + s] = acc;
  } else if (id < 16512) {
    int s = id - 16384;
    float acc = 0.f;
    for (int t = 0; t < 128; t += 4) {
      float4 a = *(const float4*)(bq + t);
      float4 b = *(const float4*)(Wk + s * 128 + t);
      acc += a.x * b.x + a.y * b.y + a.z * b.z + a.w * b.w;
    }
    bqk[s] = acc;
  }
}

// ======================= fused MLP tower (MFMA bf16), item & user =======================
// ROWS rows/block, 4 waves. B-fragments stream directly from L2-hot global with
// depth-1 register prefetch; chunk-0 issued before staging (latency hidden).
template <int ROWS, int K1, bool ITEM>
__global__ __launch_bounds__(256, 3) void mlp_kernel(
    const float* __restrict__ xmain,      // gcn_item / gcn_user
    const float* __restrict__ feat,       // item_feat / unused
    const float* __restrict__ Wg, const float* __restrict__ bg,
    const ushort* __restrict__ repB,      // unused for item
    const ushort* __restrict__ W1P, const float* __restrict__ b1,
    const ushort* __restrict__ W2P, const float* __restrict__ b2,
    float* __restrict__ outp, ushort* __restrict__ outb, int M)
{
  constexpr int RF = ROWS / 16;
  constexpr int K1CH = K1 / 32;
  constexpr int ASTR = ITEM ? 168 : 264;
  __shared__ __align__(16) ushort s_a[ROWS * 264];   // A tile, then hidden tile
  __shared__ float s_red[ROWS * 4];
  __shared__ float s_inv[ROWS];

  const int tid = threadIdx.x;
  const int wid = tid >> 6, lane = tid & 63, g = lane >> 4, q = lane & 15;
  const int i0 = blockIdx.x * ROWS;

  // ---- issue GEMM1 chunk-0 B loads NOW (L2 latency hides under A staging)
  const ushort* bbase1 = W1P + (wid * 64 + q) * 32 + g * 8;
  bf16x8 bcur[4];
  #pragma unroll
  for (int cf = 0; cf < 4; ++cf) bcur[cf] = ldfrag(bbase1 + cf * 512);

  // ---- stage A tile as bf16
  if constexpr (ITEM) {
    #pragma unroll
    for (int r = 0; r < ROWS / 8; ++r) {
      int lin = r * 256 + tid;
      int it = lin >> 5, c4 = (lin & 31) * 4;
      int row = i0 + it;
      float4 v = make_float4(0.f, 0.f, 0.f, 0.f);
      if (row < M) v = *(const float4*)(xmain + (size_t)row * GCN + c4);
      *(uint*)(&s_a[it * ASTR + GEO + c4])     = packbf2(v.x, v.y);
      *(uint*)(&s_a[it * ASTR + GEO + c4 + 2]) = packbf2(v.z, v.w);
    }
    #pragma unroll
    for (int r = 0; r < ROWS / 8; ++r) {
      int lin = r * 256 + tid;
      int it = lin >> 5, gg = lin & 31;
      int row = i0 + it;
      float f0 = 0.f, f1 = 0.f;
      if (row < M) { f0 = feat[(size_t)row * 2]; f1 = feat[(size_t)row * 2 + 1]; }
      s_a[it * ASTR + gg] = bfb(fmaxf(fmaf(f0, Wg[gg], fmaf(f1, Wg[GEO + gg], bg[gg])), 0.f));
    }
  } else {
    #pragma unroll
    for (int r = 0; r < ROWS / 8; ++r) {
      int lin = r * 256 + tid;
      int it = lin >> 5, c4 = (lin & 31) * 4;
      float4 v = *(const float4*)(xmain + (size_t)(i0 + it) * GCN + c4);
      *(uint*)(&s_a[it * ASTR + c4])     = packbf2(v.x, v.y);
      *(uint*)(&s_a[it * ASTR + c4 + 2]) = packbf2(v.z, v.w);
    }
    #pragma unroll
    for (int r = 0; r < ROWS / 16; ++r) {
      int lin = r * 256 + tid;
      int it = lin >> 4, c8 = (lin & 15) * 8;
      *(uint4*)(&s_a[it * ASTR + GCN + c8]) = *(const uint4*)(repB + (size_t)(i0 + it) * TD + c8);
    }
  }
  __syncthreads();

  // ---- GEMM1: [ROWS x K1] @ [K1 x 256], depth-1 B prefetch, barrier-free
  f32x4 acc[RF][4];
  #pragma unroll
  for (int cf = 0; cf < 4; ++cf) {
    float bv = b1[wid * 64 + cf * 16 + q];
    f32x4 t = {bv, bv, bv, bv};
    #pragma unroll
    for (int rf = 0; rf < RF; ++rf) acc[rf][cf] = t;
  }
  #pragma unroll
  for (int kb = 0; kb < K1CH; ++kb) {
    bf16x8 bnxt[4];
    if (kb + 1 < K1CH) {
      #pragma unroll
      for (int cf = 0; cf < 4; ++cf) bnxt[cf] = ldfrag(bbase1 + (kb + 1) * 8192 + cf * 512);
    }
    bf16x8 af[RF];
    #pragma unroll
    for (int rf = 0; rf < RF; ++rf) af[rf] = ldfrag(&s_a[(16 * rf + q) * ASTR + kb * 32 + g * 8]);
    #pragma unroll
    for (int rf = 0; rf < RF; ++rf)
      #pragma unroll
      for (int cf = 0; cf < 4; ++cf)
        acc[rf][cf] = __builtin_amdgcn_mfma_f32_16x16x32_bf16(af[rf], bcur[cf], acc[rf][cf], 0, 0, 0);
    if (kb + 1 < K1CH) {
      #pragma unroll
      for (int cf = 0; cf < 4; ++cf) bcur[cf] = bnxt[cf];
    }
  }

  // ---- issue GEMM2 chunk-0 B loads before the barrier (latency hides under hidden store)
  const ushort* bbase2 = W2P + (wid * 32 + q) * 32 + g * 8;
  bf16x8 b2cur[2];
  #pragma unroll
  for (int cf = 0; cf < 2; ++cf) b2cur[cf] = ldfrag(bbase2 + cf * 512);

  __syncthreads();   // all A reads done; safe to overwrite s_a with hidden

  // ---- relu(hidden) -> s_a (stride 264), direct scalar stores (2-way max, free)
  #pragma unroll
  for (int rf = 0; rf < RF; ++rf)
    #pragma unroll
    for (int cf = 0; cf < 4; ++cf)
      #pragma unroll
      for (int e = 0; e < 4; ++e)
        s_a[(16 * rf + 4 * g + e) * 264 + wid * 64 + cf * 16 + q] = bfb(fmaxf(acc[rf][cf][e], 0.f));
  __syncthreads();

  // ---- GEMM2: [ROWS x 256] @ [256 x 128], depth-1 B prefetch, barrier-free
  f32x4 acc2[RF][2];
  #pragma unroll
  for (int cf = 0; cf < 2; ++cf) {
    float bv = b2[wid * 32 + cf * 16 + q];
    f32x4 t = {bv, bv, bv, bv};
    #pragma unroll
    for (int rf = 0; rf < RF; ++rf) acc2[rf][cf] = t;
  }
  #pragma unroll
  for (int kb = 0; kb < 8; ++kb) {
    bf16x8 bnxt[2];
    if (kb < 7) {
      #pragma unroll
      for (int cf = 0; cf < 2; ++cf) bnxt[cf] = ldfrag(bbase2 + (kb + 1) * 4096 + cf * 512);
    }
    bf16x8 af[RF];
    #pragma unroll
    for (int rf = 0; rf < RF; ++rf) af[rf] = ldfrag(&s_a[(16 * rf + q) * 264 + kb * 32 + g * 8]);
    #pragma unroll
    for (int rf = 0; rf < RF; ++rf)
      #pragma unroll
      for (int cf = 0; cf < 2; ++cf)
        acc2[rf][cf] = __builtin_amdgcn_mfma_f32_16x16x32_bf16(af[rf], b2cur[cf], acc2[rf][cf], 0, 0, 0);
    if (kb < 7) {
      #pragma unroll
      for (int cf = 0; cf < 2; ++cf) b2cur[cf] = bnxt[cf];
    }
  }

  // ---- row L2-norm
  #pragma unroll
  for (int rf = 0; rf < RF; ++rf) {
    #pragma unroll
    for (int e = 0; e < 4; ++e) {
      float p = acc2[rf][0][e] * acc2[rf][0][e] + acc2[rf][1][e] * acc2[rf][1][e];
      p += __shfl_xor(p, 1, 16); p += __shfl_xor(p, 2, 16);
      p += __shfl_xor(p, 4, 16); p += __shfl_xor(p, 8, 16);
      if (q == 0) s_red[(16 * rf + 4 * g + e) * 4 + wid] = p;
    }
  }
  __syncthreads();
  if (tid < ROWS) {
    float s = s_red[tid * 4] + s_red[tid * 4 + 1] + s_red[tid * 4 + 2] + s_red[tid * 4 + 3];
    s_inv[tid] = 1.f / fmaxf(sqrtf(s), 1e-12f);
  }
  __syncthreads();

  // ---- store f32 out (+ bf16 copy for the gather, item only)
  #pragma unroll
  for (int rf = 0; rf < RF; ++rf) {
    #pragma unroll
    for (int e = 0; e < 4; ++e) {
      int row = 16 * rf + 4 * g + e;
      int grow = i0 + row;
      if (grow < M) {
        float sc = s_inv[row];
        #pragma unroll
        for (int cf = 0; cf < 2; ++cf) {
          float v = acc2[rf][cf][e] * sc;
          outp[(size_t)grow * TD + wid * 32 + cf * 16 + q] = v;
          if constexpr (ITEM) outb[(size_t)grow * TD + wid * 32 + cf * 16 + q] = bfb(v);
        }
      }
    }
  }
}

// ======================= qt = gue @ WqkS + bqk =======================
__global__ __launch_bounds__(256) void qt_kernel(
    const float* __restrict__ gcn_user, const float* __restrict__ WqkS,
    const float* __restrict__ bqk, float* __restrict__ qt)
{
  __shared__ float s_gue[16 * 132];
  const int tid = threadIdx.x;
  const int u0 = blockIdx.x * 16;
  #pragma unroll
  for (int r = 0; r < 8; ++r) {
    int lin = r * 256 + tid;
    int u = lin >> 7, c = lin & 127;
    s_gue[u * 132 + c] = gcn_user[(size_t)(u0 + u) * GCN + c];
  }
  __syncthreads();
  const int ul = tid >> 4, tx = tid & 15, c0 = tx * 8;
  float a[8];
  { float4 b4 = *(const float4*)(bqk + c0); float4 b5 = *(const float4*)(bqk + c0 + 4);
    a[0]=b4.x; a[1]=b4.y; a[2]=b4.z; a[3]=b4.w; a[4]=b5.x; a[5]=b5.y; a[6]=b5.z; a[7]=b5.w; }
  for (int g = 0; g < 128; ++g) {
    float x = s_gue[ul * 132 + g];
    float4 w4 = *(const float4*)(WqkS + g * 128 + c0);
    float4 w5 = *(const float4*)(WqkS + g * 128 + c0 + 4);
    a[0] = fmaf(x, w4.x, a[0]); a[1] = fmaf(x, w4.y, a[1]);
    a[2] = fmaf(x, w4.z, a[2]); a[3] = fmaf(x, w4.w, a[3]);
    a[4] = fmaf(x, w5.x, a[4]); a[5] = fmaf(x, w5.y, a[5]);
    a[6] = fmaf(x, w5.z, a[6]); a[7] = fmaf(x, w5.w, a[7]);
  }
  float* op = qt + (size_t)(u0 + ul) * TD + c0;
  *(float4*)op = make_float4(a[0], a[1], a[2], a[3]);
  *(float4*)(op + 4) = make_float4(a[4], a[5], a[6], a[7]);
}

// ======================= attention: one wave per user, single-pass =======================
__global__ __launch_bounds__(256) void attn_kernel(
    const int* __restrict__ user_items, const float* __restrict__ qt,
    const ushort* __restrict__ itemB, ushort* __restrict__ repB)
{
  __shared__ int s_idx[4][52];
  const int tid = threadIdx.x;
  const int wid = tid >> 6, lane = tid & 63, g = lane >> 4, q = lane & 15;
  const int u = blockIdx.x * 4 + wid;
  const int c0 = q * 8;

  if (lane < 52) s_idx[wid][lane] = (lane < 50) ? user_items[(size_t)u * RK + lane] : 0;
  float qv[8];
  { float4 a = *(const float4*)(qt + (size_t)u * TD + c0);
    float4 b = *(const float4*)(qt + (size_t)u * TD + c0 + 4);
    qv[0]=a.x; qv[1]=a.y; qv[2]=a.z; qv[3]=a.w; qv[4]=b.x; qv[5]=b.y; qv[6]=b.z; qv[7]=b.w; }
  // s_idx is wave-local (written and read by the same wave): no block barrier needed

  uint4 h[13]; float sc[13];
  #pragma unroll
  for (int i = 0; i < 13; ++i) {
    int j = 4 * i + g;
    int idx = s_idx[wid][j];
    h[i] = *(const uint4*)(itemB + (size_t)idx * TD + c0);
    float p = bflo(h[i].x) * qv[0] + bfhi(h[i].x) * qv[1]
            + bflo(h[i].y) * qv[2] + bfhi(h[i].y) * qv[3]
            + bflo(h[i].z) * qv[4] + bfhi(h[i].z) * qv[5]
            + bflo(h[i].w) * qv[6] + bfhi(h[i].w) * qv[7];
    p += __shfl_xor(p, 1, 16); p += __shfl_xor(p, 2, 16);
    p += __shfl_xor(p, 4, 16); p += __shfl_xor(p, 8, 16);
    sc[i] = (j < RK) ? p : -3.0e38f;
  }
  float m = sc[0];
  #pragma unroll
  for (int i = 1; i < 13; ++i) m = fmaxf(m, sc[i]);
  m = fmaxf(m, __shfl_xor(m, 16, 64));
  m = fmaxf(m, __shfl_xor(m, 32, 64));
  float ssum = 0.f;
  #pragma unroll
  for (int i = 0; i < 13; ++i) { sc[i] = __expf(sc[i] - m); ssum += sc[i]; }
  ssum += __shfl_xor(ssum, 16, 64);
  ssum += __shfl_xor(ssum, 32, 64);
  const float inv = 1.f / ssum;
  float rep[8] = {0, 0, 0, 0, 0, 0, 0, 0};
  #pragma unroll
  for (int i = 0; i < 13; ++i) {
    float a = sc[i] * inv;
    rep[0] = fmaf(a, bflo(h[i].x), rep[0]); rep[1] = fmaf(a, bfhi(h[i].x), rep[1]);
    rep[2] = fmaf(a, bflo(h[i].y), rep[2]); rep[3] = fmaf(a, bfhi(h[i].y), rep[3]);
    rep[4] = fmaf(a, bflo(h[i].z), rep[4]); rep[5] = fmaf(a, bfhi(h[i].z), rep[5]);
    rep[6] = fmaf(a, bflo(h[i].w), rep[6]); rep[7] = fmaf(a, bfhi(h[i].w), rep[7]);
  }
  #pragma unroll
  for (int c = 0; c < 8; ++c) {
    rep[c] += __shfl_xor(rep[c], 16, 64);
    rep[c] += __shfl_xor(rep[c], 32, 64);
  }
  if (g == 0) {
    uint4 o;
    o.x = packbf2(rep[0], rep[1]); o.y = packbf2(rep[2], rep[3]);
    o.z = packbf2(rep[4], rep[5]); o.w = packbf2(rep[6], rep[7]);
    *(uint4*)(repB + (size_t)u * TD + c0) = o;
  }
}

extern "C" void kernel_launch(void* const* d_in, const int* in_sizes, int n_in,
                              void* d_out, int out_size, void* d_ws, size_t ws_size,
                              hipStream_t stream) {
  const float* item_feat  = (const float*)d_in[0];
  const float* gcn_item   = (const float*)d_in[1];
  const float* gcn_user   = (const float*)d_in[2];
  const int*   user_items = (const int*)  d_in[3];
  const float* Wg  = (const float*)d_in[4];
  const float* bg  = (const float*)d_in[5];
  const float* Wi1 = (const float*)d_in[6];
  const float* bi1 = (const float*)d_in[7];
  const float* Wi2 = (const float*)d_in[8];
  const float* bi2 = (const float*)d_in[9];
  const float* Wq  = (const float*)d_in[10];
  const float* bq  = (const float*)d_in[11];
  const float* Wk  = (const float*)d_in[12];
  // d_in[13] = bk: softmax-invariant, dropped
  const float* Wu1 = (const float*)d_in[14];
  const float* bu1 = (const float*)d_in[15];
  const float* Wu2 = (const float*)d_in[16];
  const float* bu2 = (const float*)d_in[17];
  float* out = (float*)d_out;

  // workspace layout (bytes): ~34.3 MB total
  char* ws = (char*)d_ws;
  ushort* Wi1P  = (ushort*)(ws + 0);         // 5*256*32*2  =  81920
  ushort* Wi2P  = (ushort*)(ws + 81920);     // 8*128*32*2  =  65536
  ushort* Wu1P  = (ushort*)(ws + 147456);    // 8*256*32*2  = 131072
  ushort* Wu2P  = (ushort*)(ws + 278528);    // 8*128*32*2  =  65536
  float*  WqkS  = (float*) (ws + 344064);    // 128*128*4   =  65536
  float*  bqk   = (float*) (ws + 409600);    // 128*4       =    512
  float*  qtb   = (float*) (ws + 410112);    // 16384*128*4 = 8388608
  ushort* itemB = (ushort*)(ws + 8798720);   // 100000*128*2 = 25600000
  ushort* repB  = (ushort*)(ws + 34398720);  // 16384*128*2 = 4194304

  prep_convert<<<672, 256, 0, stream>>>(Wi1, Wi2, Wu1, Wu2, Wi1P, Wi2P, Wu1P, Wu2P);
  prep_wqk<<<65, 256, 0, stream>>>(Wq, Wk, bq, WqkS, bqk);
  qt_kernel<<<NUSERS / 16, 256, 0, stream>>>(gcn_user, WqkS, bqk, qtb);
  mlp_kernel<64, 160, true><<<(NITEMS + 63) / 64, 256, 0, stream>>>(
      gcn_item, item_feat, Wg, bg, nullptr, Wi1P, bi1, Wi2P, bi2, out, itemB, NITEMS);
  attn_kernel<<<NUSERS / 4, 256, 0, stream>>>(user_items, qtb, itemB, repB);
  mlp_kernel<32, 256, false><<<NUSERS / 32, 256, 0, stream>>>(
      gcn_user, nullptr, Wg, bg, repB, Wu1P, bu1, Wu2P, bu2, out + (size_t)NITEMS * TD, nullptr, NUSERS);
}